// Round 8
// baseline (1355.531 us; speedup 1.0000x reference)
//
#include <hip/hip_runtime.h>
#include <math.h>

#define NN 100000
#define NE 1600000
#define ET (NN + NE)
#define NBK2 391   // buckets of 256 nodes
#define EPB 8192   // edges per binscatter block
#define D2 98      // dsts per slice-chunk (1024 chunks)

typedef __attribute__((ext_vector_type(8))) __bf16 bf16x8;
typedef __attribute__((ext_vector_type(4))) float f32x4;

__device__ __forceinline__ unsigned short bf16rne(float f) {
  unsigned u = __float_as_uint(f);
  unsigned r = u + 0x7fffu + ((u >> 16) & 1u);
  return (unsigned short)(r >> 16);
}
__device__ __forceinline__ float bf16lo(unsigned u) {
  return __uint_as_float(u << 16);
}
__device__ __forceinline__ float bf16hi(unsigned u) {
  return __uint_as_float(u & 0xffff0000u);
}

// ---------------- MFMA GEMM: h2t = bf16(BN?(src) @ W) slice-major + alpha dots ----------------
// h2t layout: [8 slices of 16 ch][NN][16] (slice s = channels 16s..16s+16)
template <int K, int H, bool BN>
__global__ __launch_bounds__(256) void gemm_mfma_k(
    const float* __restrict__ xf, const float* __restrict__ W,
    const float* __restrict__ scale, const float* __restrict__ shift,
    const float* __restrict__ a_s, const float* __restrict__ a_d,
    unsigned short* __restrict__ h2t, float* __restrict__ os,
    float* __restrict__ od) {
  __shared__ unsigned short xs[64 * K];
  __shared__ unsigned short Wt[128 * K];
  const int t = threadIdx.x;
  const int w = t >> 6;
  const int l = t & 63;
  const int l15 = l & 15, g = l >> 4;
  const int row0 = blockIdx.x * 64;

  for (int idx = t; idx < K * 128; idx += 256) {
    int k = idx >> 7, c = idx & 127;
    unsigned byteoff = ((unsigned)(c * K + k) * 2u) ^ ((unsigned)(c & 7) << 4);
    *(unsigned short*)((char*)Wt + byteoff) = bf16rne(W[idx]);
  }
  for (int idx = t; idx < 64 * (K / 8); idx += 256) {
    int r = idx / (K / 8);
    int c8 = (idx % (K / 8)) * 8;
    int grow = row0 + r;
    uint4 v = {0u, 0u, 0u, 0u};
    if (grow < NN) {
      float4 f0 = *(const float4*)(xf + (size_t)grow * K + c8);
      float4 f1 = *(const float4*)(xf + (size_t)grow * K + c8 + 4);
      if (BN) {
        float4 sc0 = *(const float4*)(scale + c8);
        float4 sc1 = *(const float4*)(scale + c8 + 4);
        float4 sh0 = *(const float4*)(shift + c8);
        float4 sh1 = *(const float4*)(shift + c8 + 4);
        f0.x = fmaxf(fmaf(f0.x, sc0.x, sh0.x), 0.f);
        f0.y = fmaxf(fmaf(f0.y, sc0.y, sh0.y), 0.f);
        f0.z = fmaxf(fmaf(f0.z, sc0.z, sh0.z), 0.f);
        f0.w = fmaxf(fmaf(f0.w, sc0.w, sh0.w), 0.f);
        f1.x = fmaxf(fmaf(f1.x, sc1.x, sh1.x), 0.f);
        f1.y = fmaxf(fmaf(f1.y, sc1.y, sh1.y), 0.f);
        f1.z = fmaxf(fmaf(f1.z, sc1.z, sh1.z), 0.f);
        f1.w = fmaxf(fmaf(f1.w, sc1.w, sh1.w), 0.f);
      }
      v.x = (unsigned)bf16rne(f0.x) | ((unsigned)bf16rne(f0.y) << 16);
      v.y = (unsigned)bf16rne(f0.z) | ((unsigned)bf16rne(f0.w) << 16);
      v.z = (unsigned)bf16rne(f1.x) | ((unsigned)bf16rne(f1.y) << 16);
      v.w = (unsigned)bf16rne(f1.z) | ((unsigned)bf16rne(f1.w) << 16);
    }
    unsigned byteoff = ((unsigned)(r * K + c8) * 2u) ^ ((unsigned)(r & 7) << 4);
    *(uint4*)((char*)xs + byteoff) = v;
  }
  __syncthreads();

  f32x4 acc[8];
#pragma unroll
  for (int ct = 0; ct < 8; ct++) acc[ct] = {0.f, 0.f, 0.f, 0.f};

  const int R = w * 16 + l15;
#pragma unroll
  for (int kc = 0; kc < K; kc += 32) {
    bf16x8 a = *(const bf16x8*)((const char*)xs +
        ((((unsigned)(R * K + kc + 8 * g)) * 2u) ^ ((unsigned)(R & 7) << 4)));
#pragma unroll
    for (int ct = 0; ct < 8; ct++) {
      int c = ct * 16 + l15;
      bf16x8 b = *(const bf16x8*)((const char*)Wt +
          ((((unsigned)(c * K + kc + 8 * g)) * 2u) ^ ((unsigned)(c & 7) << 4)));
      acc[ct] = __builtin_amdgcn_mfma_f32_16x16x32_bf16(a, b, acc[ct], 0, 0, 0);
    }
  }

  float as_l[8], ad_l[8];
#pragma unroll
  for (int ct = 0; ct < 8; ct++) {
    as_l[ct] = a_s[ct * 16 + l15];
    ad_l[ct] = a_d[ct * 16 + l15];
  }

#pragma unroll
  for (int r = 0; r < 4; r++) {
    int grow = row0 + w * 16 + 4 * g + r;
    bool ok = grow < NN;
    if (ok) {
#pragma unroll
      for (int ct = 0; ct < 8; ct++)
        h2t[((size_t)ct * NN + grow) * 16 + l15] = bf16rne(acc[ct][r]);
    }
    if (H == 4) {
      float ps[4], pd[4];
#pragma unroll
      for (int hh = 0; hh < 4; hh++) {
        ps[hh] = acc[2 * hh][r] * as_l[2 * hh] + acc[2 * hh + 1][r] * as_l[2 * hh + 1];
        pd[hh] = acc[2 * hh][r] * ad_l[2 * hh] + acc[2 * hh + 1][r] * ad_l[2 * hh + 1];
      }
#pragma unroll
      for (int hh = 0; hh < 4; hh++) {
#pragma unroll
        for (int off = 1; off < 16; off <<= 1) {
          ps[hh] += __shfl_xor(ps[hh], off);
          pd[hh] += __shfl_xor(pd[hh], off);
        }
      }
      float vs = (l15 == 0) ? ps[0] : (l15 == 1) ? ps[1] : (l15 == 2) ? ps[2] : ps[3];
      float vd = (l15 == 0) ? pd[0] : (l15 == 1) ? pd[1] : (l15 == 2) ? pd[2] : pd[3];
      if (ok && l15 < 4) {
        os[grow * 4 + l15] = vs;
        od[grow * 4 + l15] = vd;
      }
    } else {
      float ps = 0.f, pd = 0.f;
#pragma unroll
      for (int ct = 0; ct < 8; ct++) {
        ps += acc[ct][r] * as_l[ct];
        pd += acc[ct][r] * ad_l[ct];
      }
#pragma unroll
      for (int off = 1; off < 16; off <<= 1) {
        ps += __shfl_xor(ps, off);
        pd += __shfl_xor(pd, off);
      }
      if (ok && l15 == 0) {
        os[grow] = ps;
        od[grow] = pd;
      }
    }
  }
}

// ---------------- CSR build: block-aggregated two-level bucket sort ----------------
__global__ __launch_bounds__(256) void histb2_k(const int* __restrict__ ei,
                                                int* __restrict__ bcnt) {
  __shared__ int h[NBK2];
  const int t = threadIdx.x;
  for (int i = t; i < NBK2; i += 256) h[i] = 0;
  __syncthreads();
#pragma unroll
  for (int k = 0; k < 4; k++) {
    int e = blockIdx.x * 1024 + k * 256 + t;
    if (e < ET) {
      int d = (e < NE) ? ei[NE + e] : e - NE;
      atomicAdd(&h[d >> 8], 1);
    }
  }
  __syncthreads();
  for (int i = t; i < NBK2; i += 256)
    if (h[i]) atomicAdd(&bcnt[i], h[i]);
}

__global__ __launch_bounds__(512) void scanb2_k(const int* __restrict__ bcnt,
                                                int* __restrict__ bbase,
                                                int* __restrict__ gpos) {
  __shared__ int tmp[512];
  const int t = threadIdx.x;
  int v = (t < NBK2) ? bcnt[t] : 0;
  tmp[t] = v;
  __syncthreads();
  for (int off = 1; off < 512; off <<= 1) {
    int x = (t >= off) ? tmp[t - off] : 0;
    __syncthreads();
    tmp[t] += x;
    __syncthreads();
  }
  if (t < NBK2) {
    int e = tmp[t] - v;
    bbase[t] = e;
    gpos[t] = e;
  }
  if (t == 0) bbase[NBK2] = ET;
}

__global__ __launch_bounds__(256) void binscatter_k(const int* __restrict__ ei,
                                                    int* __restrict__ gpos,
                                                    int2* __restrict__ tmpe) {
  __shared__ int cnt[NBK2];
  __shared__ int cur[NBK2];
  const int t = threadIdx.x;
  for (int i = t; i < NBK2; i += 256) cnt[i] = 0;
  __syncthreads();
  const int e0 = blockIdx.x * EPB;
  const int e1 = min(ET, e0 + EPB);
  for (int e = e0 + t; e < e1; e += 256) {
    int d = (e < NE) ? ei[NE + e] : e - NE;
    atomicAdd(&cnt[d >> 8], 1);
  }
  __syncthreads();
  for (int i = t; i < NBK2; i += 256) {
    int c = cnt[i];
    cur[i] = c ? atomicAdd(&gpos[i], c) : 0;
  }
  __syncthreads();
  for (int e = e0 + t; e < e1; e += 256) {
    int s, d;
    if (e < NE) { s = ei[e]; d = ei[NE + e]; } else { s = d = e - NE; }
    int p = atomicAdd(&cur[d >> 8], 1);
    int2 v; v.x = s; v.y = d;
    tmpe[p] = v;
  }
}

__global__ __launch_bounds__(256) void bucket_build2_k(
    const int2* __restrict__ tmpe, const int* __restrict__ bbase,
    int* __restrict__ rowptr, int* __restrict__ srcs) {
  const int b = blockIdx.x;
  const int t = threadIdx.x;
  const int base = bbase[b], end = bbase[b + 1];
  const int n0 = b << 8;
  __shared__ int cnt[256];
  __shared__ int off[256];
  cnt[t] = 0;
  __syncthreads();
  for (int i = base + t; i < end; i += 256) atomicAdd(&cnt[tmpe[i].y - n0], 1);
  __syncthreads();
  int myc = cnt[t];
  off[t] = myc;
  __syncthreads();
  for (int s = 1; s < 256; s <<= 1) {
    int x = (t >= s) ? off[t - s] : 0;
    __syncthreads();
    off[t] += x;
    __syncthreads();
  }
  int excl = base + off[t] - myc;
  int node = n0 + t;
  if (node < NN) rowptr[node] = excl;
  cnt[t] = excl;
  __syncthreads();
  for (int i = base + t; i < end; i += 256) {
    int2 v = tmpe[i];
    int p = atomicAdd(&cnt[v.y - n0], 1);
    srcs[p] = v.x;
  }
  if (b == 0 && t == 0) rowptr[NN] = ET;
}

// ---------------- pass 1: normalized edge weights, head-major fp16 ----------------
template <int H>
__global__ __launch_bounds__(256) void edgew_k(
    const int* __restrict__ rowptr, const int* __restrict__ srcs,
    const float* __restrict__ as, const float* __restrict__ ad,
    _Float16* __restrict__ exw) {
  const int t = threadIdx.x;
  const int wv = t >> 6, l = t & 63;
  const int gw = blockIdx.x * 4 + wv;
  const int NW = 2048 * 4;
  for (int d = gw; d < NN; d += NW) {
    const int r0 = rowptr[d], r1 = rowptr[d + 1], deg = r1 - r0;
    float adl[H];
#pragma unroll
    for (int hh = 0; hh < H; hh++) adl[hh] = ad[d * H + hh];
    if (deg <= 64) {
      float ex[H];
#pragma unroll
      for (int hh = 0; hh < H; hh++) ex[hh] = 0.f;
      if (l < deg) {
        int s = srcs[r0 + l];
        if constexpr (H == 4) {
          float4 av = *(const float4*)(as + s * 4);
          float lg;
          lg = av.x + adl[0]; lg = lg > 0.f ? lg : 0.2f * lg; ex[0] = __expf(lg);
          lg = av.y + adl[1]; lg = lg > 0.f ? lg : 0.2f * lg; ex[1] = __expf(lg);
          lg = av.z + adl[2]; lg = lg > 0.f ? lg : 0.2f * lg; ex[2] = __expf(lg);
          lg = av.w + adl[3]; lg = lg > 0.f ? lg : 0.2f * lg; ex[3] = __expf(lg);
        } else {
          float lg = as[s] + adl[0];
          lg = lg > 0.f ? lg : 0.2f * lg;
          ex[0] = __expf(lg);
        }
      }
      float inv[H];
#pragma unroll
      for (int hh = 0; hh < H; hh++) {
        float v = ex[hh];
#pragma unroll
        for (int off = 1; off < 64; off <<= 1) v += __shfl_xor(v, off);
        inv[hh] = 1.f / (v + 1e-16f);
      }
      if (l < deg) {
#pragma unroll
        for (int hh = 0; hh < H; hh++)
          exw[(size_t)hh * ET + r0 + l] = (_Float16)(ex[hh] * inv[hh]);
      }
    } else {
      float dsum[H];
#pragma unroll
      for (int hh = 0; hh < H; hh++) dsum[hh] = 0.f;
      for (int base = r0; base < r1; base += 64) {
        if (base + l < r1) {
          int s = srcs[base + l];
#pragma unroll
          for (int hh = 0; hh < H; hh++) {
            float lg = as[s * H + hh] + adl[hh];
            lg = lg > 0.f ? lg : 0.2f * lg;
            dsum[hh] += __expf(lg);
          }
        }
      }
      float inv[H];
#pragma unroll
      for (int hh = 0; hh < H; hh++) {
        float v = dsum[hh];
#pragma unroll
        for (int off = 1; off < 64; off <<= 1) v += __shfl_xor(v, off);
        inv[hh] = 1.f / (v + 1e-16f);
      }
      for (int base = r0; base < r1; base += 64) {
        if (base + l < r1) {
          int s = srcs[base + l];
#pragma unroll
          for (int hh = 0; hh < H; hh++) {
            float lg = as[s * H + hh] + adl[hh];
            lg = lg > 0.f ? lg : 0.2f * lg;
            exw[(size_t)hh * ET + base + l] = (_Float16)(__expf(lg) * inv[hh]);
          }
        }
      }
    }
  }
}

// ---------------- pass 2: slice aggregation (XCD-L2-resident h2t slice) ----------------
// grid = 8192 blocks: slice = b&7 (pins to XCD via round-robin dispatch), chunk = b>>3.
template <int H>
__global__ __launch_bounds__(256) void gat_slice_k(
    const int* __restrict__ rowptr, const int* __restrict__ srcs,
    const _Float16* __restrict__ exw, const unsigned short* __restrict__ h2t,
    const float* __restrict__ bvec, float* __restrict__ y,
    float* __restrict__ bnred2) {
  const int b = blockIdx.x;
  const int s = b & 7;
  const int chunk = b >> 3;
  const int t = threadIdx.x;
  const int wv = t >> 6, l = t & 63;
  const int p = l & 1;    // channel half (8 ch each)
  const int pe = l >> 1;  // edge slot 0..31
  const int hd = (H == 4) ? (s >> 1) : 0;
  const _Float16* exh = exw + (size_t)hd * ET;
  const unsigned short* hs = h2t + (size_t)s * NN * 16;

  const int d0 = chunk * D2;
  const int d1 = min(NN, d0 + D2);

  float s1[8], s2[8];
#pragma unroll
  for (int i = 0; i < 8; i++) { s1[i] = 0.f; s2[i] = 0.f; }
  float bv[8];
#pragma unroll
  for (int i = 0; i < 8; i++) bv[i] = bvec[s * 16 + p * 8 + i];

  for (int d = d0 + wv; d < d1; d += 4) {
    const int r0 = rowptr[d], r1 = rowptr[d + 1];
    float acc[8];
#pragma unroll
    for (int i = 0; i < 8; i++) acc[i] = 0.f;
    for (int base = r0; base < r1; base += 32) {
      int e = base + pe;
      if (e < r1) {
        int src = __builtin_nontemporal_load(&srcs[e]);
        float wgt = (float)__builtin_nontemporal_load(&exh[e]);
        uint4 u = *((const uint4*)(hs + (size_t)src * 16) + p);
        acc[0] += wgt * bf16lo(u.x);
        acc[1] += wgt * bf16hi(u.x);
        acc[2] += wgt * bf16lo(u.y);
        acc[3] += wgt * bf16hi(u.y);
        acc[4] += wgt * bf16lo(u.z);
        acc[5] += wgt * bf16hi(u.z);
        acc[6] += wgt * bf16lo(u.w);
        acc[7] += wgt * bf16hi(u.w);
      }
    }
#pragma unroll
    for (int i = 0; i < 8; i++) {
      acc[i] += __shfl_xor(acc[i], 2);
      acc[i] += __shfl_xor(acc[i], 4);
      acc[i] += __shfl_xor(acc[i], 8);
      acc[i] += __shfl_xor(acc[i], 16);
      acc[i] += __shfl_xor(acc[i], 32);
    }
    if (l < 2) {
      float o[8];
#pragma unroll
      for (int i = 0; i < 8; i++) {
        o[i] = acc[i] + bv[i];
        s1[i] += o[i];
        s2[i] += o[i] * o[i];
      }
      f32x4 w0 = {o[0], o[1], o[2], o[3]};
      f32x4 w1 = {o[4], o[5], o[6], o[7]};
      f32x4* yp = (f32x4*)(y + (size_t)d * 128 + s * 16 + p * 8);
      __builtin_nontemporal_store(w0, yp);
      __builtin_nontemporal_store(w1, yp + 1);
    }
  }

  __shared__ float bna[32];
  if (t < 32) bna[t] = 0.f;
  __syncthreads();
  if (l < 2) {
#pragma unroll
    for (int i = 0; i < 8; i++) {
      atomicAdd(&bna[p * 8 + i], s1[i]);
      atomicAdd(&bna[16 + p * 8 + i], s2[i]);
    }
  }
  __syncthreads();
  if (t < 32) atomicAdd(&bnred2[s * 32 + t], bna[t]);
}

// ---------------- BN finalize ----------------
__global__ void bn2_k(const float* __restrict__ bnred2, const float* __restrict__ g,
                      const float* __restrict__ be, float* __restrict__ scale,
                      float* __restrict__ shift) {
  int c = threadIdx.x;
  int s = c >> 4, i = c & 15;
  float mean = bnred2[s * 32 + i] / (float)NN;
  float var = bnred2[s * 32 + 16 + i] / (float)NN - mean * mean;
  float inv = rsqrtf(var + 1e-5f);
  float sc = g[c] * inv;
  scale[c] = sc;
  shift[c] = be[c] - mean * sc;
}

__global__ void bn3_k(const float* __restrict__ y, const float* __restrict__ scale,
                      const float* __restrict__ shift, float* __restrict__ out) {
  int i = blockIdx.x * blockDim.x + threadIdx.x;
  if (i >= NN * 128) return;
  int c = i & 127;
  float v = y[i] * scale[c] + shift[c];
  out[i] = v > 0.f ? v : 0.f;
}

extern "C" void kernel_launch(void* const* d_in, const int* in_sizes, int n_in,
                              void* d_out, int out_size, void* d_ws, size_t ws_size,
                              hipStream_t stream) {
  (void)in_sizes; (void)n_in; (void)out_size; (void)ws_size;
  const float* x = (const float*)d_in[0];
  const int* ei = (const int*)d_in[1];
  const float* W1 = (const float*)d_in[2];
  const float* as1 = (const float*)d_in[3];
  const float* ad1 = (const float*)d_in[4];
  const float* b1 = (const float*)d_in[5];
  const float* g1 = (const float*)d_in[6];
  const float* be1 = (const float*)d_in[7];
  const float* W2 = (const float*)d_in[8];
  const float* as2 = (const float*)d_in[9];
  const float* ad2 = (const float*)d_in[10];
  const float* b2 = (const float*)d_in[11];
  const float* g2 = (const float*)d_in[12];
  const float* be2 = (const float*)d_in[13];
  const float* W3 = (const float*)d_in[14];
  const float* as3 = (const float*)d_in[15];
  const float* ad3 = (const float*)d_in[16];
  const float* b3 = (const float*)d_in[17];
  const float* g3 = (const float*)d_in[18];
  const float* be3 = (const float*)d_in[19];

  float* Y = (float*)d_ws;                                        // [NN*128] fp32
  unsigned short* h2t = (unsigned short*)(Y + (size_t)NN * 128);  // [NN*128] bf16 slice-major
  int2* tmpe = (int2*)(h2t + (size_t)NN * 128);                   // [ET]
  _Float16* exw = (_Float16*)(tmpe + (size_t)ET);                 // [4*ET] fp16
  float* asrc = (float*)(exw + (size_t)4 * ET);                   // [NN*4]
  float* adst = asrc + (size_t)NN * 4;                            // [NN*4]
  float* bnred2 = adst + (size_t)NN * 4;                          // [256]
  float* scale = bnred2 + 256;                                    // [128]
  float* shift = scale + 128;                                     // [128]
  int* rowptr = (int*)(shift + 128);                              // [NN+2]
  int* bcnt = rowptr + NN + 2;                                    // [NBK2]
  int* bbase = bcnt + NBK2;                                       // [NBK2+1]
  int* gpos = bbase + NBK2 + 1;                                   // [NBK2]
  int* srcs = gpos + NBK2;                                        // [ET]

  const int GB64 = (NN + 63) / 64;  // 1563

  // ---- CSR build ----
  hipMemsetAsync(bcnt, 0, NBK2 * sizeof(int), stream);
  histb2_k<<<(ET + 1023) / 1024, 256, 0, stream>>>(ei, bcnt);
  scanb2_k<<<1, 512, 0, stream>>>(bcnt, bbase, gpos);
  binscatter_k<<<(ET + EPB - 1) / EPB, 256, 0, stream>>>(ei, gpos, tmpe);
  bucket_build2_k<<<NBK2, 256, 0, stream>>>(tmpe, bbase, rowptr, srcs);

  // ---- Layer 1 ----
  gemm_mfma_k<64, 4, false><<<GB64, 256, 0, stream>>>(x, W1, nullptr, nullptr,
                                                      as1, ad1, h2t, asrc, adst);
  edgew_k<4><<<2048, 256, 0, stream>>>(rowptr, srcs, asrc, adst, exw);
  hipMemsetAsync(bnred2, 0, 256 * sizeof(float), stream);
  gat_slice_k<4><<<8192, 256, 0, stream>>>(rowptr, srcs, exw, h2t, b1, Y, bnred2);
  bn2_k<<<1, 128, 0, stream>>>(bnred2, g1, be1, scale, shift);

  // ---- Layer 2 ----
  gemm_mfma_k<128, 4, true><<<GB64, 256, 0, stream>>>(Y, W2, scale, shift,
                                                      as2, ad2, h2t, asrc, adst);
  edgew_k<4><<<2048, 256, 0, stream>>>(rowptr, srcs, asrc, adst, exw);
  hipMemsetAsync(bnred2, 0, 256 * sizeof(float), stream);
  gat_slice_k<4><<<8192, 256, 0, stream>>>(rowptr, srcs, exw, h2t, b2, Y, bnred2);
  bn2_k<<<1, 128, 0, stream>>>(bnred2, g2, be2, scale, shift);

  // ---- Layer 3 ----
  gemm_mfma_k<128, 1, true><<<GB64, 256, 0, stream>>>(Y, W3, scale, shift,
                                                      as3, ad3, h2t, asrc, adst);
  edgew_k<1><<<2048, 256, 0, stream>>>(rowptr, srcs, asrc, adst, exw);
  hipMemsetAsync(bnred2, 0, 256 * sizeof(float), stream);
  gat_slice_k<1><<<8192, 256, 0, stream>>>(rowptr, srcs, exw, h2t, b3, Y, bnred2);
  bn2_k<<<1, 128, 0, stream>>>(bnred2, g3, be3, scale, shift);
  bn3_k<<<(NN * 128 + 255) / 256, 256, 0, stream>>>(Y, scale, shift, (float*)d_out);
}

// Round 9
// 1279.060 us; speedup vs baseline: 1.0598x; 1.0598x over previous
//
#include <hip/hip_runtime.h>
#include <math.h>

#define NN 100000
#define NE 1600000
#define ET (NN + NE)
#define NBK2 391   // buckets of 256 nodes
#define EPB 8192   // edges per binscatter block
#define NCH 782    // dst chunks of 128

typedef __attribute__((ext_vector_type(8))) __bf16 bf16x8;
typedef __attribute__((ext_vector_type(4))) float f32x4;

__device__ __forceinline__ unsigned short bf16rne(float f) {
  unsigned u = __float_as_uint(f);
  unsigned r = u + 0x7fffu + ((u >> 16) & 1u);
  return (unsigned short)(r >> 16);
}
__device__ __forceinline__ float bf16lo(unsigned u) {
  return __uint_as_float(u << 16);
}
__device__ __forceinline__ float bf16hi(unsigned u) {
  return __uint_as_float(u & 0xffff0000u);
}

// ---------------- MFMA GEMM: h2t = bf16(BN?(src) @ W) slice-major + alpha dots ----------------
// h2t layout: [8 slices of 16 ch][NN][16]
template <int K, int H, bool BN>
__global__ __launch_bounds__(256) void gemm_mfma_k(
    const float* __restrict__ xf, const float* __restrict__ W,
    const float* __restrict__ scale, const float* __restrict__ shift,
    const float* __restrict__ a_s, const float* __restrict__ a_d,
    unsigned short* __restrict__ h2t, float* __restrict__ os,
    float* __restrict__ od) {
  __shared__ unsigned short xs[64 * K];
  __shared__ unsigned short Wt[128 * K];
  const int t = threadIdx.x;
  const int w = t >> 6;
  const int l = t & 63;
  const int l15 = l & 15, g = l >> 4;
  const int row0 = blockIdx.x * 64;

  for (int idx = t; idx < K * 128; idx += 256) {
    int k = idx >> 7, c = idx & 127;
    unsigned byteoff = ((unsigned)(c * K + k) * 2u) ^ ((unsigned)(c & 7) << 4);
    *(unsigned short*)((char*)Wt + byteoff) = bf16rne(W[idx]);
  }
  for (int idx = t; idx < 64 * (K / 8); idx += 256) {
    int r = idx / (K / 8);
    int c8 = (idx % (K / 8)) * 8;
    int grow = row0 + r;
    uint4 v = {0u, 0u, 0u, 0u};
    if (grow < NN) {
      float4 f0 = *(const float4*)(xf + (size_t)grow * K + c8);
      float4 f1 = *(const float4*)(xf + (size_t)grow * K + c8 + 4);
      if (BN) {
        float4 sc0 = *(const float4*)(scale + c8);
        float4 sc1 = *(const float4*)(scale + c8 + 4);
        float4 sh0 = *(const float4*)(shift + c8);
        float4 sh1 = *(const float4*)(shift + c8 + 4);
        f0.x = fmaxf(fmaf(f0.x, sc0.x, sh0.x), 0.f);
        f0.y = fmaxf(fmaf(f0.y, sc0.y, sh0.y), 0.f);
        f0.z = fmaxf(fmaf(f0.z, sc0.z, sh0.z), 0.f);
        f0.w = fmaxf(fmaf(f0.w, sc0.w, sh0.w), 0.f);
        f1.x = fmaxf(fmaf(f1.x, sc1.x, sh1.x), 0.f);
        f1.y = fmaxf(fmaf(f1.y, sc1.y, sh1.y), 0.f);
        f1.z = fmaxf(fmaf(f1.z, sc1.z, sh1.z), 0.f);
        f1.w = fmaxf(fmaf(f1.w, sc1.w, sh1.w), 0.f);
      }
      v.x = (unsigned)bf16rne(f0.x) | ((unsigned)bf16rne(f0.y) << 16);
      v.y = (unsigned)bf16rne(f0.z) | ((unsigned)bf16rne(f0.w) << 16);
      v.z = (unsigned)bf16rne(f1.x) | ((unsigned)bf16rne(f1.y) << 16);
      v.w = (unsigned)bf16rne(f1.z) | ((unsigned)bf16rne(f1.w) << 16);
    }
    unsigned byteoff = ((unsigned)(r * K + c8) * 2u) ^ ((unsigned)(r & 7) << 4);
    *(uint4*)((char*)xs + byteoff) = v;
  }
  __syncthreads();

  f32x4 acc[8];
#pragma unroll
  for (int ct = 0; ct < 8; ct++) acc[ct] = {0.f, 0.f, 0.f, 0.f};

  const int R = w * 16 + l15;
#pragma unroll
  for (int kc = 0; kc < K; kc += 32) {
    bf16x8 a = *(const bf16x8*)((const char*)xs +
        ((((unsigned)(R * K + kc + 8 * g)) * 2u) ^ ((unsigned)(R & 7) << 4)));
#pragma unroll
    for (int ct = 0; ct < 8; ct++) {
      int c = ct * 16 + l15;
      bf16x8 b = *(const bf16x8*)((const char*)Wt +
          ((((unsigned)(c * K + kc + 8 * g)) * 2u) ^ ((unsigned)(c & 7) << 4)));
      acc[ct] = __builtin_amdgcn_mfma_f32_16x16x32_bf16(a, b, acc[ct], 0, 0, 0);
    }
  }

  float as_l[8], ad_l[8];
#pragma unroll
  for (int ct = 0; ct < 8; ct++) {
    as_l[ct] = a_s[ct * 16 + l15];
    ad_l[ct] = a_d[ct * 16 + l15];
  }

#pragma unroll
  for (int r = 0; r < 4; r++) {
    int grow = row0 + w * 16 + 4 * g + r;
    bool ok = grow < NN;
    if (ok) {
#pragma unroll
      for (int ct = 0; ct < 8; ct++)
        h2t[((size_t)ct * NN + grow) * 16 + l15] = bf16rne(acc[ct][r]);
    }
    if (H == 4) {
      float ps[4], pd[4];
#pragma unroll
      for (int hh = 0; hh < 4; hh++) {
        ps[hh] = acc[2 * hh][r] * as_l[2 * hh] + acc[2 * hh + 1][r] * as_l[2 * hh + 1];
        pd[hh] = acc[2 * hh][r] * ad_l[2 * hh] + acc[2 * hh + 1][r] * ad_l[2 * hh + 1];
      }
#pragma unroll
      for (int hh = 0; hh < 4; hh++) {
#pragma unroll
        for (int off = 1; off < 16; off <<= 1) {
          ps[hh] += __shfl_xor(ps[hh], off);
          pd[hh] += __shfl_xor(pd[hh], off);
        }
      }
      float vs = (l15 == 0) ? ps[0] : (l15 == 1) ? ps[1] : (l15 == 2) ? ps[2] : ps[3];
      float vd = (l15 == 0) ? pd[0] : (l15 == 1) ? pd[1] : (l15 == 2) ? pd[2] : pd[3];
      if (ok && l15 < 4) {
        os[grow * 4 + l15] = vs;
        od[grow * 4 + l15] = vd;
      }
    } else {
      float ps = 0.f, pd = 0.f;
#pragma unroll
      for (int ct = 0; ct < 8; ct++) {
        ps += acc[ct][r] * as_l[ct];
        pd += acc[ct][r] * ad_l[ct];
      }
#pragma unroll
      for (int off = 1; off < 16; off <<= 1) {
        ps += __shfl_xor(ps, off);
        pd += __shfl_xor(pd, off);
      }
      if (ok && l15 == 0) {
        os[grow] = ps;
        od[grow] = pd;
      }
    }
  }
}

// ---------------- CSR build: block-aggregated two-level bucket sort ----------------
__global__ __launch_bounds__(256) void histb2_k(const int* __restrict__ ei,
                                                int* __restrict__ bcnt) {
  __shared__ int h[NBK2];
  const int t = threadIdx.x;
  for (int i = t; i < NBK2; i += 256) h[i] = 0;
  __syncthreads();
#pragma unroll
  for (int k = 0; k < 4; k++) {
    int e = blockIdx.x * 1024 + k * 256 + t;
    if (e < ET) {
      int d = (e < NE) ? ei[NE + e] : e - NE;
      atomicAdd(&h[d >> 8], 1);
    }
  }
  __syncthreads();
  for (int i = t; i < NBK2; i += 256)
    if (h[i]) atomicAdd(&bcnt[i], h[i]);
}

__global__ __launch_bounds__(512) void scanb2_k(const int* __restrict__ bcnt,
                                                int* __restrict__ bbase,
                                                int* __restrict__ gpos) {
  __shared__ int tmp[512];
  const int t = threadIdx.x;
  int v = (t < NBK2) ? bcnt[t] : 0;
  tmp[t] = v;
  __syncthreads();
  for (int off = 1; off < 512; off <<= 1) {
    int x = (t >= off) ? tmp[t - off] : 0;
    __syncthreads();
    tmp[t] += x;
    __syncthreads();
  }
  if (t < NBK2) {
    int e = tmp[t] - v;
    bbase[t] = e;
    gpos[t] = e;
  }
  if (t == 0) bbase[NBK2] = ET;
}

__global__ __launch_bounds__(256) void binscatter_k(const int* __restrict__ ei,
                                                    int* __restrict__ gpos,
                                                    int2* __restrict__ tmpe) {
  __shared__ int cnt[NBK2];
  __shared__ int cur[NBK2];
  const int t = threadIdx.x;
  for (int i = t; i < NBK2; i += 256) cnt[i] = 0;
  __syncthreads();
  const int e0 = blockIdx.x * EPB;
  const int e1 = min(ET, e0 + EPB);
  for (int e = e0 + t; e < e1; e += 256) {
    int d = (e < NE) ? ei[NE + e] : e - NE;
    atomicAdd(&cnt[d >> 8], 1);
  }
  __syncthreads();
  for (int i = t; i < NBK2; i += 256) {
    int c = cnt[i];
    cur[i] = c ? atomicAdd(&gpos[i], c) : 0;
  }
  __syncthreads();
  for (int e = e0 + t; e < e1; e += 256) {
    int s, d;
    if (e < NE) { s = ei[e]; d = ei[NE + e]; } else { s = d = e - NE; }
    int p = atomicAdd(&cur[d >> 8], 1);
    int2 v; v.x = s; v.y = d;
    tmpe[p] = v;
  }
}

__global__ __launch_bounds__(256) void bucket_build2_k(
    const int2* __restrict__ tmpe, const int* __restrict__ bbase,
    int* __restrict__ rowptr, int* __restrict__ srcs) {
  const int b = blockIdx.x;
  const int t = threadIdx.x;
  const int base = bbase[b], end = bbase[b + 1];
  const int n0 = b << 8;
  __shared__ int cnt[256];
  __shared__ int off[256];
  cnt[t] = 0;
  __syncthreads();
  for (int i = base + t; i < end; i += 256) atomicAdd(&cnt[tmpe[i].y - n0], 1);
  __syncthreads();
  int myc = cnt[t];
  off[t] = myc;
  __syncthreads();
  for (int s = 1; s < 256; s <<= 1) {
    int x = (t >= s) ? off[t - s] : 0;
    __syncthreads();
    off[t] += x;
    __syncthreads();
  }
  int excl = base + off[t] - myc;
  int node = n0 + t;
  if (node < NN) rowptr[node] = excl;
  cnt[t] = excl;
  __syncthreads();
  for (int i = base + t; i < end; i += 256) {
    int2 v = tmpe[i];
    int p = atomicAdd(&cnt[v.y - n0], 1);
    srcs[p] = v.x;
  }
  if (b == 0 && t == 0) rowptr[NN] = ET;
}

// ---------------- pass 1: normalized edge weights, head-major fp16 ----------------
template <int H>
__global__ __launch_bounds__(256) void edgew_k(
    const int* __restrict__ rowptr, const int* __restrict__ srcs,
    const float* __restrict__ as, const float* __restrict__ ad,
    _Float16* __restrict__ exw) {
  const int t = threadIdx.x;
  const int wv = t >> 6, l = t & 63;
  const int gw = blockIdx.x * 4 + wv;
  const int NW = 2048 * 4;
  for (int d = gw; d < NN; d += NW) {
    const int r0 = rowptr[d], r1 = rowptr[d + 1], deg = r1 - r0;
    float adl[H];
#pragma unroll
    for (int hh = 0; hh < H; hh++) adl[hh] = ad[d * H + hh];
    if (deg <= 64) {
      float ex[H];
#pragma unroll
      for (int hh = 0; hh < H; hh++) ex[hh] = 0.f;
      if (l < deg) {
        int s = srcs[r0 + l];
        if constexpr (H == 4) {
          float4 av = *(const float4*)(as + s * 4);
          float lg;
          lg = av.x + adl[0]; lg = lg > 0.f ? lg : 0.2f * lg; ex[0] = __expf(lg);
          lg = av.y + adl[1]; lg = lg > 0.f ? lg : 0.2f * lg; ex[1] = __expf(lg);
          lg = av.z + adl[2]; lg = lg > 0.f ? lg : 0.2f * lg; ex[2] = __expf(lg);
          lg = av.w + adl[3]; lg = lg > 0.f ? lg : 0.2f * lg; ex[3] = __expf(lg);
        } else {
          float lg = as[s] + adl[0];
          lg = lg > 0.f ? lg : 0.2f * lg;
          ex[0] = __expf(lg);
        }
      }
      float inv[H];
#pragma unroll
      for (int hh = 0; hh < H; hh++) {
        float v = ex[hh];
#pragma unroll
        for (int off = 1; off < 64; off <<= 1) v += __shfl_xor(v, off);
        inv[hh] = 1.f / (v + 1e-16f);
      }
      if (l < deg) {
#pragma unroll
        for (int hh = 0; hh < H; hh++)
          exw[(size_t)hh * ET + r0 + l] = (_Float16)(ex[hh] * inv[hh]);
      }
    } else {
      float dsum[H];
#pragma unroll
      for (int hh = 0; hh < H; hh++) dsum[hh] = 0.f;
      for (int base = r0; base < r1; base += 64) {
        if (base + l < r1) {
          int s = srcs[base + l];
#pragma unroll
          for (int hh = 0; hh < H; hh++) {
            float lg = as[s * H + hh] + adl[hh];
            lg = lg > 0.f ? lg : 0.2f * lg;
            dsum[hh] += __expf(lg);
          }
        }
      }
      float inv[H];
#pragma unroll
      for (int hh = 0; hh < H; hh++) {
        float v = dsum[hh];
#pragma unroll
        for (int off = 1; off < 64; off <<= 1) v += __shfl_xor(v, off);
        inv[hh] = 1.f / (v + 1e-16f);
      }
      for (int base = r0; base < r1; base += 64) {
        if (base + l < r1) {
          int s = srcs[base + l];
#pragma unroll
          for (int hh = 0; hh < H; hh++) {
            float lg = as[s * H + hh] + adl[hh];
            lg = lg > 0.f ? lg : 0.2f * lg;
            exw[(size_t)hh * ET + base + l] = (_Float16)(__expf(lg) * inv[hh]);
          }
        }
      }
    }
  }
}

// ---------------- pass 2: slice aggregation, lane-serial (no reductions) ----------------
// grid = NCH*8: slice = b&7 (XCD pin), chunk = b>>3 covers 128 dsts.
// Each lane pair owns one dst: lane p in {0,1} accumulates 8 channels serially.
template <int H>
__global__ __launch_bounds__(256) void gat_slice_k(
    const int* __restrict__ rowptr, const int* __restrict__ srcs,
    const _Float16* __restrict__ exw, const unsigned short* __restrict__ h2t,
    const float* __restrict__ bvec, float* __restrict__ y,
    float* __restrict__ bnred2) {
  const int b = blockIdx.x;
  const int s = b & 7;
  const int chunk = b >> 3;
  const int t = threadIdx.x;
  const int p = t & 1;    // channel half (8 ch)
  const int dl = t >> 1;  // dst 0..127 within chunk
  const int d = chunk * 128 + dl;
  const int hd = (H == 4) ? (s >> 1) : 0;
  const _Float16* exh = exw + (size_t)hd * ET;
  const unsigned short* hs = h2t + (size_t)s * NN * 16;

  float s1[8], s2[8];
#pragma unroll
  for (int i = 0; i < 8; i++) { s1[i] = 0.f; s2[i] = 0.f; }

  if (d < NN) {
    const int r0 = rowptr[d], r1 = rowptr[d + 1];
    float acc[8];
#pragma unroll
    for (int i = 0; i < 8; i++) acc[i] = 0.f;
    for (int e = r0; e < r1; e++) {
      int src = __builtin_nontemporal_load(&srcs[e]);
      float wgt = (float)exh[e];
      uint4 u = *((const uint4*)(hs + (size_t)src * 16) + p);
      acc[0] += wgt * bf16lo(u.x);
      acc[1] += wgt * bf16hi(u.x);
      acc[2] += wgt * bf16lo(u.y);
      acc[3] += wgt * bf16hi(u.y);
      acc[4] += wgt * bf16lo(u.z);
      acc[5] += wgt * bf16hi(u.z);
      acc[6] += wgt * bf16lo(u.w);
      acc[7] += wgt * bf16hi(u.w);
    }
    float o[8];
#pragma unroll
    for (int i = 0; i < 8; i++) {
      o[i] = acc[i] + bvec[s * 16 + p * 8 + i];
      s1[i] += o[i];
      s2[i] += o[i] * o[i];
    }
    f32x4 w0 = {o[0], o[1], o[2], o[3]};
    f32x4 w1 = {o[4], o[5], o[6], o[7]};
    f32x4* yp = (f32x4*)(y + (size_t)d * 128 + s * 16 + p * 8);
    __builtin_nontemporal_store(w0, yp);
    __builtin_nontemporal_store(w1, yp + 1);
  }

  __shared__ float bna[32];
  if (t < 32) bna[t] = 0.f;
  __syncthreads();
#pragma unroll
  for (int i = 0; i < 8; i++) {
    atomicAdd(&bna[p * 8 + i], s1[i]);
    atomicAdd(&bna[16 + p * 8 + i], s2[i]);
  }
  __syncthreads();
  if (t < 32) atomicAdd(&bnred2[s * 32 + t], bna[t]);
}

// ---------------- BN finalize ----------------
__global__ void bn2_k(const float* __restrict__ bnred2, const float* __restrict__ g,
                      const float* __restrict__ be, float* __restrict__ scale,
                      float* __restrict__ shift) {
  int c = threadIdx.x;
  int s = c >> 4, i = c & 15;
  float mean = bnred2[s * 32 + i] / (float)NN;
  float var = bnred2[s * 32 + 16 + i] / (float)NN - mean * mean;
  float inv = rsqrtf(var + 1e-5f);
  float sc = g[c] * inv;
  scale[c] = sc;
  shift[c] = be[c] - mean * sc;
}

__global__ void bn3_k(const float* __restrict__ y, const float* __restrict__ scale,
                      const float* __restrict__ shift, float* __restrict__ out) {
  int i = blockIdx.x * blockDim.x + threadIdx.x;
  if (i >= NN * 128) return;
  int c = i & 127;
  float v = y[i] * scale[c] + shift[c];
  out[i] = v > 0.f ? v : 0.f;
}

extern "C" void kernel_launch(void* const* d_in, const int* in_sizes, int n_in,
                              void* d_out, int out_size, void* d_ws, size_t ws_size,
                              hipStream_t stream) {
  (void)in_sizes; (void)n_in; (void)out_size; (void)ws_size;
  const float* x = (const float*)d_in[0];
  const int* ei = (const int*)d_in[1];
  const float* W1 = (const float*)d_in[2];
  const float* as1 = (const float*)d_in[3];
  const float* ad1 = (const float*)d_in[4];
  const float* b1 = (const float*)d_in[5];
  const float* g1 = (const float*)d_in[6];
  const float* be1 = (const float*)d_in[7];
  const float* W2 = (const float*)d_in[8];
  const float* as2 = (const float*)d_in[9];
  const float* ad2 = (const float*)d_in[10];
  const float* b2 = (const float*)d_in[11];
  const float* g2 = (const float*)d_in[12];
  const float* be2 = (const float*)d_in[13];
  const float* W3 = (const float*)d_in[14];
  const float* as3 = (const float*)d_in[15];
  const float* ad3 = (const float*)d_in[16];
  const float* b3 = (const float*)d_in[17];
  const float* g3 = (const float*)d_in[18];
  const float* be3 = (const float*)d_in[19];

  float* Y = (float*)d_ws;                                        // [NN*128] fp32
  unsigned short* h2t = (unsigned short*)(Y + (size_t)NN * 128);  // [NN*128] bf16 slice-major
  int2* tmpe = (int2*)(h2t + (size_t)NN * 128);                   // [ET]
  _Float16* exw = (_Float16*)(tmpe + (size_t)ET);                 // [4*ET] fp16
  float* asrc = (float*)(exw + (size_t)4 * ET);                   // [NN*4]
  float* adst = asrc + (size_t)NN * 4;                            // [NN*4]
  float* bnred2 = adst + (size_t)NN * 4;                          // [256]
  float* scale = bnred2 + 256;                                    // [128]
  float* shift = scale + 128;                                     // [128]
  int* rowptr = (int*)(shift + 128);                              // [NN+2]
  int* bcnt = rowptr + NN + 2;                                    // [NBK2]
  int* bbase = bcnt + NBK2;                                       // [NBK2+1]
  int* gpos = bbase + NBK2 + 1;                                   // [NBK2]
  int* srcs = gpos + NBK2;                                        // [ET]

  const int GB64 = (NN + 63) / 64;  // 1563
  const int GSL = NCH * 8;          // 6256

  // ---- CSR build ----
  hipMemsetAsync(bcnt, 0, NBK2 * sizeof(int), stream);
  histb2_k<<<(ET + 1023) / 1024, 256, 0, stream>>>(ei, bcnt);
  scanb2_k<<<1, 512, 0, stream>>>(bcnt, bbase, gpos);
  binscatter_k<<<(ET + EPB - 1) / EPB, 256, 0, stream>>>(ei, gpos, tmpe);
  bucket_build2_k<<<NBK2, 256, 0, stream>>>(tmpe, bbase, rowptr, srcs);

  // ---- Layer 1 ----
  gemm_mfma_k<64, 4, false><<<GB64, 256, 0, stream>>>(x, W1, nullptr, nullptr,
                                                      as1, ad1, h2t, asrc, adst);
  edgew_k<4><<<2048, 256, 0, stream>>>(rowptr, srcs, asrc, adst, exw);
  hipMemsetAsync(bnred2, 0, 256 * sizeof(float), stream);
  gat_slice_k<4><<<GSL, 256, 0, stream>>>(rowptr, srcs, exw, h2t, b1, Y, bnred2);
  bn2_k<<<1, 128, 0, stream>>>(bnred2, g1, be1, scale, shift);

  // ---- Layer 2 ----
  gemm_mfma_k<128, 4, true><<<GB64, 256, 0, stream>>>(Y, W2, scale, shift,
                                                      as2, ad2, h2t, asrc, adst);
  edgew_k<4><<<2048, 256, 0, stream>>>(rowptr, srcs, asrc, adst, exw);
  hipMemsetAsync(bnred2, 0, 256 * sizeof(float), stream);
  gat_slice_k<4><<<GSL, 256, 0, stream>>>(rowptr, srcs, exw, h2t, b2, Y, bnred2);
  bn2_k<<<1, 128, 0, stream>>>(bnred2, g2, be2, scale, shift);

  // ---- Layer 3 ----
  gemm_mfma_k<128, 1, true><<<GB64, 256, 0, stream>>>(Y, W3, scale, shift,
                                                      as3, ad3, h2t, asrc, adst);
  edgew_k<1><<<2048, 256, 0, stream>>>(rowptr, srcs, asrc, adst, exw);
  hipMemsetAsync(bnred2, 0, 256 * sizeof(float), stream);
  gat_slice_k<1><<<GSL, 256, 0, stream>>>(rowptr, srcs, exw, h2t, b3, Y, bnred2);
  bn2_k<<<1, 128, 0, stream>>>(bnred2, g3, be3, scale, shift);
  bn3_k<<<(NN * 128 + 255) / 256, 256, 0, stream>>>(Y, scale, shift, (float*)d_out);
}

// Round 10
// 691.700 us; speedup vs baseline: 1.9597x; 1.8492x over previous
//
#include <hip/hip_runtime.h>
#include <math.h>

#define NN 100000
#define NE 1600000
#define ET (NN + NE)
#define NBK2 391   // buckets of 256 nodes
#define EPB 8192   // edges per binscatter block
#define D2 98      // dsts per slice-chunk
#define NCH2 1021  // ceil(NN/D2)

typedef __attribute__((ext_vector_type(8))) __bf16 bf16x8;
typedef __attribute__((ext_vector_type(4))) float f32x4;

__device__ __forceinline__ unsigned short bf16rne(float f) {
  unsigned u = __float_as_uint(f);
  unsigned r = u + 0x7fffu + ((u >> 16) & 1u);
  return (unsigned short)(r >> 16);
}
__device__ __forceinline__ float bf16lo(unsigned u) {
  return __uint_as_float(u << 16);
}
__device__ __forceinline__ float bf16hi(unsigned u) {
  return __uint_as_float(u & 0xffff0000u);
}

// ---------------- MFMA GEMM: h2t = bf16(BN?(src) @ W) slice-major + alpha dots ----------------
// h2t layout: [8 slices of 16 ch][NN][16]
template <int K, int H, bool BN>
__global__ __launch_bounds__(256) void gemm_mfma_k(
    const float* __restrict__ xf, const float* __restrict__ W,
    const float* __restrict__ scale, const float* __restrict__ shift,
    const float* __restrict__ a_s, const float* __restrict__ a_d,
    unsigned short* __restrict__ h2t, float* __restrict__ os,
    float* __restrict__ od) {
  __shared__ unsigned short xs[64 * K];
  __shared__ unsigned short Wt[128 * K];
  const int t = threadIdx.x;
  const int w = t >> 6;
  const int l = t & 63;
  const int l15 = l & 15, g = l >> 4;
  const int row0 = blockIdx.x * 64;

  for (int idx = t; idx < K * 128; idx += 256) {
    int k = idx >> 7, c = idx & 127;
    unsigned byteoff = ((unsigned)(c * K + k) * 2u) ^ ((unsigned)(c & 7) << 4);
    *(unsigned short*)((char*)Wt + byteoff) = bf16rne(W[idx]);
  }
  for (int idx = t; idx < 64 * (K / 8); idx += 256) {
    int r = idx / (K / 8);
    int c8 = (idx % (K / 8)) * 8;
    int grow = row0 + r;
    uint4 v = {0u, 0u, 0u, 0u};
    if (grow < NN) {
      float4 f0 = *(const float4*)(xf + (size_t)grow * K + c8);
      float4 f1 = *(const float4*)(xf + (size_t)grow * K + c8 + 4);
      if (BN) {
        float4 sc0 = *(const float4*)(scale + c8);
        float4 sc1 = *(const float4*)(scale + c8 + 4);
        float4 sh0 = *(const float4*)(shift + c8);
        float4 sh1 = *(const float4*)(shift + c8 + 4);
        f0.x = fmaxf(fmaf(f0.x, sc0.x, sh0.x), 0.f);
        f0.y = fmaxf(fmaf(f0.y, sc0.y, sh0.y), 0.f);
        f0.z = fmaxf(fmaf(f0.z, sc0.z, sh0.z), 0.f);
        f0.w = fmaxf(fmaf(f0.w, sc0.w, sh0.w), 0.f);
        f1.x = fmaxf(fmaf(f1.x, sc1.x, sh1.x), 0.f);
        f1.y = fmaxf(fmaf(f1.y, sc1.y, sh1.y), 0.f);
        f1.z = fmaxf(fmaf(f1.z, sc1.z, sh1.z), 0.f);
        f1.w = fmaxf(fmaf(f1.w, sc1.w, sh1.w), 0.f);
      }
      v.x = (unsigned)bf16rne(f0.x) | ((unsigned)bf16rne(f0.y) << 16);
      v.y = (unsigned)bf16rne(f0.z) | ((unsigned)bf16rne(f0.w) << 16);
      v.z = (unsigned)bf16rne(f1.x) | ((unsigned)bf16rne(f1.y) << 16);
      v.w = (unsigned)bf16rne(f1.z) | ((unsigned)bf16rne(f1.w) << 16);
    }
    unsigned byteoff = ((unsigned)(r * K + c8) * 2u) ^ ((unsigned)(r & 7) << 4);
    *(uint4*)((char*)xs + byteoff) = v;
  }
  __syncthreads();

  f32x4 acc[8];
#pragma unroll
  for (int ct = 0; ct < 8; ct++) acc[ct] = {0.f, 0.f, 0.f, 0.f};

  const int R = w * 16 + l15;
#pragma unroll
  for (int kc = 0; kc < K; kc += 32) {
    bf16x8 a = *(const bf16x8*)((const char*)xs +
        ((((unsigned)(R * K + kc + 8 * g)) * 2u) ^ ((unsigned)(R & 7) << 4)));
#pragma unroll
    for (int ct = 0; ct < 8; ct++) {
      int c = ct * 16 + l15;
      bf16x8 b = *(const bf16x8*)((const char*)Wt +
          ((((unsigned)(c * K + kc + 8 * g)) * 2u) ^ ((unsigned)(c & 7) << 4)));
      acc[ct] = __builtin_amdgcn_mfma_f32_16x16x32_bf16(a, b, acc[ct], 0, 0, 0);
    }
  }

  float as_l[8], ad_l[8];
#pragma unroll
  for (int ct = 0; ct < 8; ct++) {
    as_l[ct] = a_s[ct * 16 + l15];
    ad_l[ct] = a_d[ct * 16 + l15];
  }

#pragma unroll
  for (int r = 0; r < 4; r++) {
    int grow = row0 + w * 16 + 4 * g + r;
    bool ok = grow < NN;
    if (ok) {
#pragma unroll
      for (int ct = 0; ct < 8; ct++)
        h2t[((size_t)ct * NN + grow) * 16 + l15] = bf16rne(acc[ct][r]);
    }
    if (H == 4) {
      float ps[4], pd[4];
#pragma unroll
      for (int hh = 0; hh < 4; hh++) {
        ps[hh] = acc[2 * hh][r] * as_l[2 * hh] + acc[2 * hh + 1][r] * as_l[2 * hh + 1];
        pd[hh] = acc[2 * hh][r] * ad_l[2 * hh] + acc[2 * hh + 1][r] * ad_l[2 * hh + 1];
      }
#pragma unroll
      for (int hh = 0; hh < 4; hh++) {
#pragma unroll
        for (int off = 1; off < 16; off <<= 1) {
          ps[hh] += __shfl_xor(ps[hh], off);
          pd[hh] += __shfl_xor(pd[hh], off);
        }
      }
      float vs = (l15 == 0) ? ps[0] : (l15 == 1) ? ps[1] : (l15 == 2) ? ps[2] : ps[3];
      float vd = (l15 == 0) ? pd[0] : (l15 == 1) ? pd[1] : (l15 == 2) ? pd[2] : pd[3];
      if (ok && l15 < 4) {
        os[grow * 4 + l15] = vs;
        od[grow * 4 + l15] = vd;
      }
    } else {
      float ps = 0.f, pd = 0.f;
#pragma unroll
      for (int ct = 0; ct < 8; ct++) {
        ps += acc[ct][r] * as_l[ct];
        pd += acc[ct][r] * ad_l[ct];
      }
#pragma unroll
      for (int off = 1; off < 16; off <<= 1) {
        ps += __shfl_xor(ps, off);
        pd += __shfl_xor(pd, off);
      }
      if (ok && l15 == 0) {
        os[grow] = ps;
        od[grow] = pd;
      }
    }
  }
}

// ---------------- CSR build: block-aggregated two-level bucket sort ----------------
__global__ __launch_bounds__(256) void histb2_k(const int* __restrict__ ei,
                                                int* __restrict__ bcnt) {
  __shared__ int h[NBK2];
  const int t = threadIdx.x;
  for (int i = t; i < NBK2; i += 256) h[i] = 0;
  __syncthreads();
#pragma unroll
  for (int k = 0; k < 4; k++) {
    int e = blockIdx.x * 1024 + k * 256 + t;
    if (e < ET) {
      int d = (e < NE) ? ei[NE + e] : e - NE;
      atomicAdd(&h[d >> 8], 1);
    }
  }
  __syncthreads();
  for (int i = t; i < NBK2; i += 256)
    if (h[i]) atomicAdd(&bcnt[i], h[i]);
}

__global__ __launch_bounds__(512) void scanb2_k(const int* __restrict__ bcnt,
                                                int* __restrict__ bbase,
                                                int* __restrict__ gpos) {
  __shared__ int tmp[512];
  const int t = threadIdx.x;
  int v = (t < NBK2) ? bcnt[t] : 0;
  tmp[t] = v;
  __syncthreads();
  for (int off = 1; off < 512; off <<= 1) {
    int x = (t >= off) ? tmp[t - off] : 0;
    __syncthreads();
    tmp[t] += x;
    __syncthreads();
  }
  if (t < NBK2) {
    int e = tmp[t] - v;
    bbase[t] = e;
    gpos[t] = e;
  }
  if (t == 0) bbase[NBK2] = ET;
}

__global__ __launch_bounds__(256) void binscatter_k(const int* __restrict__ ei,
                                                    int* __restrict__ gpos,
                                                    int2* __restrict__ tmpe) {
  __shared__ int cnt[NBK2];
  __shared__ int cur[NBK2];
  const int t = threadIdx.x;
  for (int i = t; i < NBK2; i += 256) cnt[i] = 0;
  __syncthreads();
  const int e0 = blockIdx.x * EPB;
  const int e1 = min(ET, e0 + EPB);
  for (int e = e0 + t; e < e1; e += 256) {
    int d = (e < NE) ? ei[NE + e] : e - NE;
    atomicAdd(&cnt[d >> 8], 1);
  }
  __syncthreads();
  for (int i = t; i < NBK2; i += 256) {
    int c = cnt[i];
    cur[i] = c ? atomicAdd(&gpos[i], c) : 0;
  }
  __syncthreads();
  for (int e = e0 + t; e < e1; e += 256) {
    int s, d;
    if (e < NE) { s = ei[e]; d = ei[NE + e]; } else { s = d = e - NE; }
    int p = atomicAdd(&cur[d >> 8], 1);
    int2 v; v.x = s; v.y = d;
    tmpe[p] = v;
  }
}

__global__ __launch_bounds__(256) void bucket_build2_k(
    const int2* __restrict__ tmpe, const int* __restrict__ bbase,
    int* __restrict__ rowptr, int* __restrict__ srcs) {
  const int b = blockIdx.x;
  const int t = threadIdx.x;
  const int base = bbase[b], end = bbase[b + 1];
  const int n0 = b << 8;
  __shared__ int cnt[256];
  __shared__ int off[256];
  cnt[t] = 0;
  __syncthreads();
  for (int i = base + t; i < end; i += 256) atomicAdd(&cnt[tmpe[i].y - n0], 1);
  __syncthreads();
  int myc = cnt[t];
  off[t] = myc;
  __syncthreads();
  for (int s = 1; s < 256; s <<= 1) {
    int x = (t >= s) ? off[t - s] : 0;
    __syncthreads();
    off[t] += x;
    __syncthreads();
  }
  int excl = base + off[t] - myc;
  int node = n0 + t;
  if (node < NN) rowptr[node] = excl;
  cnt[t] = excl;
  __syncthreads();
  for (int i = base + t; i < end; i += 256) {
    int2 v = tmpe[i];
    int p = atomicAdd(&cnt[v.y - n0], 1);
    srcs[p] = v.x;
  }
  if (b == 0 && t == 0) rowptr[NN] = ET;
}

// ---------------- pass 1: normalized edge weights, head-major fp16 ----------------
template <int H>
__global__ __launch_bounds__(256) void edgew_k(
    const int* __restrict__ rowptr, const int* __restrict__ srcs,
    const float* __restrict__ as, const float* __restrict__ ad,
    _Float16* __restrict__ exw) {
  const int t = threadIdx.x;
  const int wv = t >> 6, l = t & 63;
  const int gw = blockIdx.x * 4 + wv;
  const int NW = 2048 * 4;
  for (int d = gw; d < NN; d += NW) {
    const int r0 = rowptr[d], r1 = rowptr[d + 1], deg = r1 - r0;
    float adl[H];
#pragma unroll
    for (int hh = 0; hh < H; hh++) adl[hh] = ad[d * H + hh];
    if (deg <= 64) {
      float ex[H];
#pragma unroll
      for (int hh = 0; hh < H; hh++) ex[hh] = 0.f;
      if (l < deg) {
        int s = srcs[r0 + l];
        if constexpr (H == 4) {
          float4 av = *(const float4*)(as + s * 4);
          float lg;
          lg = av.x + adl[0]; lg = lg > 0.f ? lg : 0.2f * lg; ex[0] = __expf(lg);
          lg = av.y + adl[1]; lg = lg > 0.f ? lg : 0.2f * lg; ex[1] = __expf(lg);
          lg = av.z + adl[2]; lg = lg > 0.f ? lg : 0.2f * lg; ex[2] = __expf(lg);
          lg = av.w + adl[3]; lg = lg > 0.f ? lg : 0.2f * lg; ex[3] = __expf(lg);
        } else {
          float lg = as[s] + adl[0];
          lg = lg > 0.f ? lg : 0.2f * lg;
          ex[0] = __expf(lg);
        }
      }
      float inv[H];
#pragma unroll
      for (int hh = 0; hh < H; hh++) {
        float v = ex[hh];
#pragma unroll
        for (int off = 1; off < 64; off <<= 1) v += __shfl_xor(v, off);
        inv[hh] = 1.f / (v + 1e-16f);
      }
      if (l < deg) {
#pragma unroll
        for (int hh = 0; hh < H; hh++)
          exw[(size_t)hh * ET + r0 + l] = (_Float16)(ex[hh] * inv[hh]);
      }
    } else {
      float dsum[H];
#pragma unroll
      for (int hh = 0; hh < H; hh++) dsum[hh] = 0.f;
      for (int base = r0; base < r1; base += 64) {
        if (base + l < r1) {
          int s = srcs[base + l];
#pragma unroll
          for (int hh = 0; hh < H; hh++) {
            float lg = as[s * H + hh] + adl[hh];
            lg = lg > 0.f ? lg : 0.2f * lg;
            dsum[hh] += __expf(lg);
          }
        }
      }
      float inv[H];
#pragma unroll
      for (int hh = 0; hh < H; hh++) {
        float v = dsum[hh];
#pragma unroll
        for (int off = 1; off < 64; off <<= 1) v += __shfl_xor(v, off);
        inv[hh] = 1.f / (v + 1e-16f);
      }
      for (int base = r0; base < r1; base += 64) {
        if (base + l < r1) {
          int s = srcs[base + l];
#pragma unroll
          for (int hh = 0; hh < H; hh++) {
            float lg = as[s * H + hh] + adl[hh];
            lg = lg > 0.f ? lg : 0.2f * lg;
            exw[(size_t)hh * ET + base + l] = (_Float16)(__expf(lg) * inv[hh]);
          }
        }
      }
    }
  }
}

// ---------------- pass 2: slice aggregation, 8 dsts x 4 slots x 2 halves per wave ----------------
// grid = NCH2*8: slice = b&7 (XCD pin), chunk = b>>3 covers D2 dsts.
// Wave-coherent slot access (R8 cache pattern) + cheap 2-level slot reduction.
template <int H>
__global__ __launch_bounds__(256) void gat_slice_k(
    const int* __restrict__ rowptr, const int* __restrict__ srcs,
    const _Float16* __restrict__ exw, const unsigned short* __restrict__ h2t,
    const float* __restrict__ bvec, float* __restrict__ y,
    float* __restrict__ bnred2) {
  const int b = blockIdx.x;
  const int s = b & 7;
  const int chunk = b >> 3;
  const int t = threadIdx.x;
  const int wv = t >> 6, l = t & 63;
  const int dl = l >> 3;          // local dst 0..7
  const int slot = (l >> 1) & 3;  // edge slot 0..3
  const int p = l & 1;            // 16B half
  const int hd = (H == 4) ? (s >> 1) : 0;
  const _Float16* exh = exw + (size_t)hd * ET;
  const unsigned short* hs = h2t + (size_t)s * NN * 16;

  float s1[8], s2[8];
#pragma unroll
  for (int i = 0; i < 8; i++) { s1[i] = 0.f; s2[i] = 0.f; }
  float bv[8];
#pragma unroll
  for (int i = 0; i < 8; i++) bv[i] = bvec[s * 16 + p * 8 + i];

  const int d0 = chunk * D2;
  for (int dbase = wv * 8; dbase < D2; dbase += 32) {
    int dli = dbase + dl;
    int d = d0 + dli;
    bool ok = (dli < D2) && (d < NN);
    int r0 = 0, r1 = 0;
    if (ok) { r0 = rowptr[d]; r1 = rowptr[d + 1]; }
    float acc[8];
#pragma unroll
    for (int i = 0; i < 8; i++) acc[i] = 0.f;
    for (int e = r0 + slot; e < r1; e += 4) {
      int src = srcs[e];
      float wgt = (float)exh[e];
      uint4 u = *((const uint4*)(hs + (size_t)src * 16) + p);
      acc[0] += wgt * bf16lo(u.x);
      acc[1] += wgt * bf16hi(u.x);
      acc[2] += wgt * bf16lo(u.y);
      acc[3] += wgt * bf16hi(u.y);
      acc[4] += wgt * bf16lo(u.z);
      acc[5] += wgt * bf16hi(u.z);
      acc[6] += wgt * bf16lo(u.w);
      acc[7] += wgt * bf16hi(u.w);
    }
    // reduce over slot dim (lane bits 1-2)
#pragma unroll
    for (int i = 0; i < 8; i++) {
      acc[i] += __shfl_xor(acc[i], 2);
      acc[i] += __shfl_xor(acc[i], 4);
    }
    if (ok && slot == 0) {
      float o[8];
#pragma unroll
      for (int i = 0; i < 8; i++) {
        o[i] = acc[i] + bv[i];
        s1[i] += o[i];
        s2[i] += o[i] * o[i];
      }
      f32x4 w0 = {o[0], o[1], o[2], o[3]};
      f32x4 w1 = {o[4], o[5], o[6], o[7]};
      f32x4* yp = (f32x4*)(y + (size_t)d * 128 + s * 16 + p * 8);
      __builtin_nontemporal_store(w0, yp);
      __builtin_nontemporal_store(w1, yp + 1);
    }
  }

  __shared__ float bna[32];
  if (t < 32) bna[t] = 0.f;
  __syncthreads();
  if (slot == 0) {
#pragma unroll
    for (int i = 0; i < 8; i++) {
      atomicAdd(&bna[p * 8 + i], s1[i]);
      atomicAdd(&bna[16 + p * 8 + i], s2[i]);
    }
  }
  __syncthreads();
  if (t < 32) atomicAdd(&bnred2[s * 32 + t], bna[t]);
}

// ---------------- BN finalize ----------------
__global__ void bn2_k(const float* __restrict__ bnred2, const float* __restrict__ g,
                      const float* __restrict__ be, float* __restrict__ scale,
                      float* __restrict__ shift) {
  int c = threadIdx.x;
  int s = c >> 4, i = c & 15;
  float mean = bnred2[s * 32 + i] / (float)NN;
  float var = bnred2[s * 32 + 16 + i] / (float)NN - mean * mean;
  float inv = rsqrtf(var + 1e-5f);
  float sc = g[c] * inv;
  scale[c] = sc;
  shift[c] = be[c] - mean * sc;
}

__global__ void bn3_k(const float* __restrict__ y, const float* __restrict__ scale,
                      const float* __restrict__ shift, float* __restrict__ out) {
  int i = blockIdx.x * blockDim.x + threadIdx.x;
  if (i >= NN * 128) return;
  int c = i & 127;
  float v = y[i] * scale[c] + shift[c];
  out[i] = v > 0.f ? v : 0.f;
}

extern "C" void kernel_launch(void* const* d_in, const int* in_sizes, int n_in,
                              void* d_out, int out_size, void* d_ws, size_t ws_size,
                              hipStream_t stream) {
  (void)in_sizes; (void)n_in; (void)out_size; (void)ws_size;
  const float* x = (const float*)d_in[0];
  const int* ei = (const int*)d_in[1];
  const float* W1 = (const float*)d_in[2];
  const float* as1 = (const float*)d_in[3];
  const float* ad1 = (const float*)d_in[4];
  const float* b1 = (const float*)d_in[5];
  const float* g1 = (const float*)d_in[6];
  const float* be1 = (const float*)d_in[7];
  const float* W2 = (const float*)d_in[8];
  const float* as2 = (const float*)d_in[9];
  const float* ad2 = (const float*)d_in[10];
  const float* b2 = (const float*)d_in[11];
  const float* g2 = (const float*)d_in[12];
  const float* be2 = (const float*)d_in[13];
  const float* W3 = (const float*)d_in[14];
  const float* as3 = (const float*)d_in[15];
  const float* ad3 = (const float*)d_in[16];
  const float* b3 = (const float*)d_in[17];
  const float* g3 = (const float*)d_in[18];
  const float* be3 = (const float*)d_in[19];

  float* Y = (float*)d_ws;                                        // [NN*128] fp32
  unsigned short* h2t = (unsigned short*)(Y + (size_t)NN * 128);  // [NN*128] bf16 slice-major
  int2* tmpe = (int2*)(h2t + (size_t)NN * 128);                   // [ET]
  _Float16* exw = (_Float16*)(tmpe + (size_t)ET);                 // [4*ET] fp16
  float* asrc = (float*)(exw + (size_t)4 * ET);                   // [NN*4]
  float* adst = asrc + (size_t)NN * 4;                            // [NN*4]
  float* bnred2 = adst + (size_t)NN * 4;                          // [256]
  float* scale = bnred2 + 256;                                    // [128]
  float* shift = scale + 128;                                     // [128]
  int* rowptr = (int*)(shift + 128);                              // [NN+2]
  int* bcnt = rowptr + NN + 2;                                    // [NBK2]
  int* bbase = bcnt + NBK2;                                       // [NBK2+1]
  int* gpos = bbase + NBK2 + 1;                                   // [NBK2]
  int* srcs = gpos + NBK2;                                        // [ET]

  const int GB64 = (NN + 63) / 64;  // 1563
  const int GSL = NCH2 * 8;         // 8168

  // ---- CSR build ----
  hipMemsetAsync(bcnt, 0, NBK2 * sizeof(int), stream);
  histb2_k<<<(ET + 1023) / 1024, 256, 0, stream>>>(ei, bcnt);
  scanb2_k<<<1, 512, 0, stream>>>(bcnt, bbase, gpos);
  binscatter_k<<<(ET + EPB - 1) / EPB, 256, 0, stream>>>(ei, gpos, tmpe);
  bucket_build2_k<<<NBK2, 256, 0, stream>>>(tmpe, bbase, rowptr, srcs);

  // ---- Layer 1 ----
  gemm_mfma_k<64, 4, false><<<GB64, 256, 0, stream>>>(x, W1, nullptr, nullptr,
                                                      as1, ad1, h2t, asrc, adst);
  edgew_k<4><<<2048, 256, 0, stream>>>(rowptr, srcs, asrc, adst, exw);
  hipMemsetAsync(bnred2, 0, 256 * sizeof(float), stream);
  gat_slice_k<4><<<GSL, 256, 0, stream>>>(rowptr, srcs, exw, h2t, b1, Y, bnred2);
  bn2_k<<<1, 128, 0, stream>>>(bnred2, g1, be1, scale, shift);

  // ---- Layer 2 ----
  gemm_mfma_k<128, 4, true><<<GB64, 256, 0, stream>>>(Y, W2, scale, shift,
                                                      as2, ad2, h2t, asrc, adst);
  edgew_k<4><<<2048, 256, 0, stream>>>(rowptr, srcs, asrc, adst, exw);
  hipMemsetAsync(bnred2, 0, 256 * sizeof(float), stream);
  gat_slice_k<4><<<GSL, 256, 0, stream>>>(rowptr, srcs, exw, h2t, b2, Y, bnred2);
  bn2_k<<<1, 128, 0, stream>>>(bnred2, g2, be2, scale, shift);

  // ---- Layer 3 ----
  gemm_mfma_k<128, 1, true><<<GB64, 256, 0, stream>>>(Y, W3, scale, shift,
                                                      as3, ad3, h2t, asrc, adst);
  edgew_k<1><<<2048, 256, 0, stream>>>(rowptr, srcs, asrc, adst, exw);
  hipMemsetAsync(bnred2, 0, 256 * sizeof(float), stream);
  gat_slice_k<1><<<GSL, 256, 0, stream>>>(rowptr, srcs, exw, h2t, b3, Y, bnred2);
  bn2_k<<<1, 128, 0, stream>>>(bnred2, g3, be3, scale, shift);
  bn3_k<<<(NN * 128 + 255) / 256, 256, 0, stream>>>(Y, scale, shift, (float*)d_out);
}

// Round 12
// 588.797 us; speedup vs baseline: 2.3022x; 1.1748x over previous
//
#include <hip/hip_runtime.h>
#include <math.h>

#define NN 100000
#define NE 1600000
#define ET (NN + NE)
#define NBK2 391   // buckets of 256 nodes
#define EPB 8192   // edges per binscatter block
#define NGAT 2048

typedef __attribute__((ext_vector_type(8))) __bf16 bf16x8;
typedef __attribute__((ext_vector_type(4))) float f32x4;

__device__ __forceinline__ unsigned short bf16rne(float f) {
  unsigned u = __float_as_uint(f);
  unsigned r = u + 0x7fffu + ((u >> 16) & 1u);
  return (unsigned short)(r >> 16);
}
__device__ __forceinline__ float bf16lo(unsigned u) {
  return __uint_as_float(u << 16);
}
__device__ __forceinline__ float bf16hi(unsigned u) {
  return __uint_as_float(u & 0xffff0000u);
}

// ---------------- MFMA GEMM: h2 = bf16(BN?(x) @ W) + fused alpha dots ----------------
// BN=false: x is fp32 (layer 1). BN=true: x is bf16 y-buffer, BN+ReLU in staging.
template <int K, int H, bool BN>
__global__ __launch_bounds__(256) void gemm_mfma_k(
    const void* __restrict__ xin, const float* __restrict__ W,
    const float* __restrict__ scale, const float* __restrict__ shift,
    const float* __restrict__ a_s, const float* __restrict__ a_d,
    unsigned short* __restrict__ h2, float* __restrict__ os,
    float* __restrict__ od) {
  __shared__ unsigned short xs[64 * K];
  __shared__ unsigned short Wt[128 * K];
  const int t = threadIdx.x;
  const int w = t >> 6;
  const int l = t & 63;
  const int l15 = l & 15, g = l >> 4;
  const int row0 = blockIdx.x * 64;

  for (int idx = t; idx < K * 128; idx += 256) {
    int k = idx >> 7, c = idx & 127;
    unsigned byteoff = ((unsigned)(c * K + k) * 2u) ^ ((unsigned)(c & 7) << 4);
    *(unsigned short*)((char*)Wt + byteoff) = bf16rne(W[idx]);
  }
  for (int idx = t; idx < 64 * (K / 8); idx += 256) {
    int r = idx / (K / 8);
    int c8 = (idx % (K / 8)) * 8;
    int grow = row0 + r;
    uint4 v = {0u, 0u, 0u, 0u};
    if (grow < NN) {
      if (BN) {
        const unsigned short* xb = (const unsigned short*)xin;
        uint4 raw = *(const uint4*)(xb + (size_t)grow * K + c8);
        float4 sc0 = *(const float4*)(scale + c8);
        float4 sc1 = *(const float4*)(scale + c8 + 4);
        float4 sh0 = *(const float4*)(shift + c8);
        float4 sh1 = *(const float4*)(shift + c8 + 4);
        float f0 = fmaxf(fmaf(bf16lo(raw.x), sc0.x, sh0.x), 0.f);
        float f1 = fmaxf(fmaf(bf16hi(raw.x), sc0.y, sh0.y), 0.f);
        float f2 = fmaxf(fmaf(bf16lo(raw.y), sc0.z, sh0.z), 0.f);
        float f3 = fmaxf(fmaf(bf16hi(raw.y), sc0.w, sh0.w), 0.f);
        float f4 = fmaxf(fmaf(bf16lo(raw.z), sc1.x, sh1.x), 0.f);
        float f5 = fmaxf(fmaf(bf16hi(raw.z), sc1.y, sh1.y), 0.f);
        float f6 = fmaxf(fmaf(bf16lo(raw.w), sc1.z, sh1.z), 0.f);
        float f7 = fmaxf(fmaf(bf16hi(raw.w), sc1.w, sh1.w), 0.f);
        v.x = (unsigned)bf16rne(f0) | ((unsigned)bf16rne(f1) << 16);
        v.y = (unsigned)bf16rne(f2) | ((unsigned)bf16rne(f3) << 16);
        v.z = (unsigned)bf16rne(f4) | ((unsigned)bf16rne(f5) << 16);
        v.w = (unsigned)bf16rne(f6) | ((unsigned)bf16rne(f7) << 16);
      } else {
        const float* xf = (const float*)xin;
        float4 f0 = *(const float4*)(xf + (size_t)grow * K + c8);
        float4 f1 = *(const float4*)(xf + (size_t)grow * K + c8 + 4);
        v.x = (unsigned)bf16rne(f0.x) | ((unsigned)bf16rne(f0.y) << 16);
        v.y = (unsigned)bf16rne(f0.z) | ((unsigned)bf16rne(f0.w) << 16);
        v.z = (unsigned)bf16rne(f1.x) | ((unsigned)bf16rne(f1.y) << 16);
        v.w = (unsigned)bf16rne(f1.z) | ((unsigned)bf16rne(f1.w) << 16);
      }
    }
    unsigned byteoff = ((unsigned)(r * K + c8) * 2u) ^ ((unsigned)(r & 7) << 4);
    *(uint4*)((char*)xs + byteoff) = v;
  }
  __syncthreads();

  f32x4 acc[8];
#pragma unroll
  for (int ct = 0; ct < 8; ct++) acc[ct] = {0.f, 0.f, 0.f, 0.f};

  const int R = w * 16 + l15;
#pragma unroll
  for (int kc = 0; kc < K; kc += 32) {
    bf16x8 a = *(const bf16x8*)((const char*)xs +
        ((((unsigned)(R * K + kc + 8 * g)) * 2u) ^ ((unsigned)(R & 7) << 4)));
#pragma unroll
    for (int ct = 0; ct < 8; ct++) {
      int c = ct * 16 + l15;
      bf16x8 b = *(const bf16x8*)((const char*)Wt +
          ((((unsigned)(c * K + kc + 8 * g)) * 2u) ^ ((unsigned)(c & 7) << 4)));
      acc[ct] = __builtin_amdgcn_mfma_f32_16x16x32_bf16(a, b, acc[ct], 0, 0, 0);
    }
  }

  float as_l[8], ad_l[8];
#pragma unroll
  for (int ct = 0; ct < 8; ct++) {
    as_l[ct] = a_s[ct * 16 + l15];
    ad_l[ct] = a_d[ct * 16 + l15];
  }

#pragma unroll
  for (int r = 0; r < 4; r++) {
    int grow = row0 + w * 16 + 4 * g + r;
    bool ok = grow < NN;
    if (ok) {
#pragma unroll
      for (int ct = 0; ct < 8; ct++)
        h2[(size_t)grow * 128 + ct * 16 + l15] = bf16rne(acc[ct][r]);
    }
    if (H == 4) {
      float ps[4], pd[4];
#pragma unroll
      for (int hh = 0; hh < 4; hh++) {
        ps[hh] = acc[2 * hh][r] * as_l[2 * hh] + acc[2 * hh + 1][r] * as_l[2 * hh + 1];
        pd[hh] = acc[2 * hh][r] * ad_l[2 * hh] + acc[2 * hh + 1][r] * ad_l[2 * hh + 1];
      }
#pragma unroll
      for (int hh = 0; hh < 4; hh++) {
#pragma unroll
        for (int off = 1; off < 16; off <<= 1) {
          ps[hh] += __shfl_xor(ps[hh], off);
          pd[hh] += __shfl_xor(pd[hh], off);
        }
      }
      float vs = (l15 == 0) ? ps[0] : (l15 == 1) ? ps[1] : (l15 == 2) ? ps[2] : ps[3];
      float vd = (l15 == 0) ? pd[0] : (l15 == 1) ? pd[1] : (l15 == 2) ? pd[2] : pd[3];
      if (ok && l15 < 4) {
        os[grow * 4 + l15] = vs;
        od[grow * 4 + l15] = vd;
      }
    } else {
      float ps = 0.f, pd = 0.f;
#pragma unroll
      for (int ct = 0; ct < 8; ct++) {
        ps += acc[ct][r] * as_l[ct];
        pd += acc[ct][r] * ad_l[ct];
      }
#pragma unroll
      for (int off = 1; off < 16; off <<= 1) {
        ps += __shfl_xor(ps, off);
        pd += __shfl_xor(pd, off);
      }
      if (ok && l15 == 0) {
        os[grow] = ps;
        od[grow] = pd;
      }
    }
  }
}

// ---------------- CSR build: block-aggregated two-level bucket sort ----------------
__global__ __launch_bounds__(256) void histb2_k(const int* __restrict__ ei,
                                                int* __restrict__ bcnt) {
  __shared__ int h[NBK2];
  const int t = threadIdx.x;
  for (int i = t; i < NBK2; i += 256) h[i] = 0;
  __syncthreads();
#pragma unroll
  for (int k = 0; k < 4; k++) {
    int e = blockIdx.x * 1024 + k * 256 + t;
    if (e < ET) {
      int d = (e < NE) ? ei[NE + e] : e - NE;
      atomicAdd(&h[d >> 8], 1);
    }
  }
  __syncthreads();
  for (int i = t; i < NBK2; i += 256)
    if (h[i]) atomicAdd(&bcnt[i], h[i]);
}

__global__ __launch_bounds__(512) void scanb2_k(const int* __restrict__ bcnt,
                                                int* __restrict__ bbase,
                                                int* __restrict__ gpos) {
  __shared__ int tmp[512];
  const int t = threadIdx.x;
  int v = (t < NBK2) ? bcnt[t] : 0;
  tmp[t] = v;
  __syncthreads();
  for (int off = 1; off < 512; off <<= 1) {
    int x = (t >= off) ? tmp[t - off] : 0;
    __syncthreads();
    tmp[t] += x;
    __syncthreads();
  }
  if (t < NBK2) {
    int e = tmp[t] - v;
    bbase[t] = e;
    gpos[t] = e;
  }
  if (t == 0) bbase[NBK2] = ET;
}

__global__ __launch_bounds__(256) void binscatter_k(const int* __restrict__ ei,
                                                    int* __restrict__ gpos,
                                                    int2* __restrict__ tmpe) {
  __shared__ int cnt[NBK2];
  __shared__ int cur[NBK2];
  const int t = threadIdx.x;
  for (int i = t; i < NBK2; i += 256) cnt[i] = 0;
  __syncthreads();
  const int e0 = blockIdx.x * EPB;
  const int e1 = min(ET, e0 + EPB);
  for (int e = e0 + t; e < e1; e += 256) {
    int d = (e < NE) ? ei[NE + e] : e - NE;
    atomicAdd(&cnt[d >> 8], 1);
  }
  __syncthreads();
  for (int i = t; i < NBK2; i += 256) {
    int c = cnt[i];
    cur[i] = c ? atomicAdd(&gpos[i], c) : 0;
  }
  __syncthreads();
  for (int e = e0 + t; e < e1; e += 256) {
    int s, d;
    if (e < NE) { s = ei[e]; d = ei[NE + e]; } else { s = d = e - NE; }
    int p = atomicAdd(&cur[d >> 8], 1);
    int2 v; v.x = s; v.y = d;
    tmpe[p] = v;
  }
}

__global__ __launch_bounds__(256) void bucket_build2_k(
    const int2* __restrict__ tmpe, const int* __restrict__ bbase,
    int* __restrict__ rowptr, int* __restrict__ srcs) {
  const int b = blockIdx.x;
  const int t = threadIdx.x;
  const int base = bbase[b], end = bbase[b + 1];
  const int n0 = b << 8;
  __shared__ int cnt[256];
  __shared__ int off[256];
  cnt[t] = 0;
  __syncthreads();
  for (int i = base + t; i < end; i += 256) atomicAdd(&cnt[tmpe[i].y - n0], 1);
  __syncthreads();
  int myc = cnt[t];
  off[t] = myc;
  __syncthreads();
  for (int s = 1; s < 256; s <<= 1) {
    int x = (t >= s) ? off[t - s] : 0;
    __syncthreads();
    off[t] += x;
    __syncthreads();
  }
  int excl = base + off[t] - myc;
  int node = n0 + t;
  if (node < NN) rowptr[node] = excl;
  cnt[t] = excl;
  __syncthreads();
  for (int i = base + t; i < end; i += 256) {
    int2 v = tmpe[i];
    int p = atomicAdd(&cnt[v.y - n0], 1);
    srcs[p] = v.x;
  }
  if (b == 0 && t == 0) rowptr[NN] = ET;
}

// ---------------- GAT aggregation: persistent, one wave per node, fused BN stats ----------------
// y output is bf16.
template <int H, int C>
__global__ __launch_bounds__(256) void gat_agg_k(
    const int* __restrict__ rowptr, const int* __restrict__ srcs,
    const float* __restrict__ as, const float* __restrict__ ad,
    const unsigned short* __restrict__ h2, const float* __restrict__ bvec,
    unsigned short* __restrict__ y, float* __restrict__ bnred) {
  const int t = threadIdx.x;
  const int wv = t >> 6, l = t & 63;
  const int l15 = l & 15, g4 = l >> 4;
  __shared__ int ssh[4][64];
  __shared__ float exsh[4][64 * H];
  __shared__ float bna[256];
  bna[t] = 0.f;
  __syncthreads();

  const int hc = (l15 * 8) / C;
  float s1[8], s2[8];
#pragma unroll
  for (int i = 0; i < 8; i++) { s1[i] = 0.f; s2[i] = 0.f; }

  float4 bv0 = {0, 0, 0, 0}, bv1 = {0, 0, 0, 0};
  if (l < 16) {
    bv0 = *(const float4*)(bvec + l * 8);
    bv1 = *(const float4*)(bvec + l * 8 + 4);
  }

  const uint4* h4 = (const uint4*)h2;
  const int gw = blockIdx.x * 4 + wv;
  const int NW = NGAT * 4;

  for (int d = gw; d < NN; d += NW) {
    const int r0 = rowptr[d], r1 = rowptr[d + 1];
    float adl[H];
#pragma unroll
    for (int hh = 0; hh < H; hh++) adl[hh] = ad[d * H + hh];
    float acc[8];
#pragma unroll
    for (int i = 0; i < 8; i++) acc[i] = 0.f;
    float dsum[H];
#pragma unroll
    for (int hh = 0; hh < H; hh++) dsum[hh] = 0.f;

    for (int base = r0; base < r1; base += 64) {
      int cnt = min(64, r1 - base);
      __builtin_amdgcn_wave_barrier();
      if (l < cnt) {
        int s = srcs[base + l];
        ssh[wv][l] = s;
        if (H == 4) {
          float4 av = *(const float4*)(as + s * 4);
          float lg, ex;
          lg = av.x + adl[0]; lg = lg > 0.f ? lg : 0.2f * lg; ex = __expf(lg);
          exsh[wv][l * 4 + 0] = ex; dsum[0] += ex;
          lg = av.y + adl[1]; lg = lg > 0.f ? lg : 0.2f * lg; ex = __expf(lg);
          exsh[wv][l * 4 + 1] = ex; dsum[1] += ex;
          lg = av.z + adl[2]; lg = lg > 0.f ? lg : 0.2f * lg; ex = __expf(lg);
          exsh[wv][l * 4 + 2] = ex; dsum[2] += ex;
          lg = av.w + adl[3]; lg = lg > 0.f ? lg : 0.2f * lg; ex = __expf(lg);
          exsh[wv][l * 4 + 3] = ex; dsum[3] += ex;
        } else {
          float lg = as[s] + adl[0];
          lg = lg > 0.f ? lg : 0.2f * lg;
          float ex = __expf(lg);
          exsh[wv][l] = ex;
          dsum[0] += ex;
        }
      }
      __builtin_amdgcn_wave_barrier();
      int full = cnt >> 2;
      for (int jj = 0; jj < full; jj++) {
        int grp = jj * 4 + g4;
        int row = ssh[wv][grp];
        uint4 u = h4[(size_t)row * 16 + l15];
        float wgt = exsh[wv][grp * H + hc];
        acc[0] += wgt * bf16lo(u.x);
        acc[1] += wgt * bf16hi(u.x);
        acc[2] += wgt * bf16lo(u.y);
        acc[3] += wgt * bf16hi(u.y);
        acc[4] += wgt * bf16lo(u.z);
        acc[5] += wgt * bf16hi(u.z);
        acc[6] += wgt * bf16lo(u.w);
        acc[7] += wgt * bf16hi(u.w);
      }
      if (cnt & 3) {
        int grp = full * 4 + g4;
        if (g4 < (cnt & 3)) {
          int row = ssh[wv][grp];
          uint4 u = h4[(size_t)row * 16 + l15];
          float wgt = exsh[wv][grp * H + hc];
          acc[0] += wgt * bf16lo(u.x);
          acc[1] += wgt * bf16hi(u.x);
          acc[2] += wgt * bf16lo(u.y);
          acc[3] += wgt * bf16hi(u.y);
          acc[4] += wgt * bf16lo(u.z);
          acc[5] += wgt * bf16hi(u.z);
          acc[6] += wgt * bf16lo(u.w);
          acc[7] += wgt * bf16hi(u.w);
        }
      }
      __builtin_amdgcn_wave_barrier();
    }

#pragma unroll
    for (int i = 0; i < 8; i++) {
      acc[i] += __shfl_xor(acc[i], 16);
      acc[i] += __shfl_xor(acc[i], 32);
    }
#pragma unroll
    for (int hh = 0; hh < H; hh++) {
#pragma unroll
      for (int off = 1; off < 64; off <<= 1) dsum[hh] += __shfl_xor(dsum[hh], off);
    }

    if (l < 16) {
      float inv = 1.f / (dsum[hc] + 1e-16f);
      float o[8];
      o[0] = acc[0] * inv + bv0.x;
      o[1] = acc[1] * inv + bv0.y;
      o[2] = acc[2] * inv + bv0.z;
      o[3] = acc[3] * inv + bv0.w;
      o[4] = acc[4] * inv + bv1.x;
      o[5] = acc[5] * inv + bv1.y;
      o[6] = acc[6] * inv + bv1.z;
      o[7] = acc[7] * inv + bv1.w;
      uint4 pk;
      pk.x = (unsigned)bf16rne(o[0]) | ((unsigned)bf16rne(o[1]) << 16);
      pk.y = (unsigned)bf16rne(o[2]) | ((unsigned)bf16rne(o[3]) << 16);
      pk.z = (unsigned)bf16rne(o[4]) | ((unsigned)bf16rne(o[5]) << 16);
      pk.w = (unsigned)bf16rne(o[6]) | ((unsigned)bf16rne(o[7]) << 16);
      *(uint4*)(y + (size_t)d * 128 + l * 8) = pk;
#pragma unroll
      for (int i = 0; i < 8; i++) {
        s1[i] += o[i];
        s2[i] += o[i] * o[i];
      }
    }
  }

  if (l < 16) {
#pragma unroll
    for (int i = 0; i < 8; i++) {
      atomicAdd(&bna[l15 * 8 + i], s1[i]);
      atomicAdd(&bna[128 + l15 * 8 + i], s2[i]);
    }
  }
  __syncthreads();
  atomicAdd(&bnred[t], bna[t]);
}

// ---------------- BN finalize ----------------
__global__ void bn2_k(const float* __restrict__ bnred, const float* __restrict__ g,
                      const float* __restrict__ be, float* __restrict__ scale,
                      float* __restrict__ shift) {
  int c = threadIdx.x;
  float mean = bnred[c] / (float)NN;
  float var = bnred[128 + c] / (float)NN - mean * mean;
  float inv = rsqrtf(var + 1e-5f);
  float sc = g[c] * inv;
  scale[c] = sc;
  shift[c] = be[c] - mean * sc;
}

// final BN apply + ReLU: bf16 y -> fp32 out
__global__ __launch_bounds__(256) void bn3_k(const unsigned short* __restrict__ y,
                                             const float* __restrict__ scale,
                                             const float* __restrict__ shift,
                                             float* __restrict__ out) {
  int i = blockIdx.x * 256 + threadIdx.x;  // 8-channel unit
  if (i >= NN * 16) return;
  int c = (i * 8) & 127;
  uint4 raw = *(const uint4*)(y + (size_t)i * 8);
  float4 sc0 = *(const float4*)(scale + c);
  float4 sc1 = *(const float4*)(scale + c + 4);
  float4 sh0 = *(const float4*)(shift + c);
  float4 sh1 = *(const float4*)(shift + c + 4);
  float4 o0, o1;
  o0.x = fmaxf(fmaf(bf16lo(raw.x), sc0.x, sh0.x), 0.f);
  o0.y = fmaxf(fmaf(bf16hi(raw.x), sc0.y, sh0.y), 0.f);
  o0.z = fmaxf(fmaf(bf16lo(raw.y), sc0.z, sh0.z), 0.f);
  o0.w = fmaxf(fmaf(bf16hi(raw.y), sc0.w, sh0.w), 0.f);
  o1.x = fmaxf(fmaf(bf16lo(raw.z), sc1.x, sh1.x), 0.f);
  o1.y = fmaxf(fmaf(bf16hi(raw.z), sc1.y, sh1.y), 0.f);
  o1.z = fmaxf(fmaf(bf16lo(raw.w), sc1.z, sh1.z), 0.f);
  o1.w = fmaxf(fmaf(bf16hi(raw.w), sc1.w, sh1.w), 0.f);
  *(float4*)(out + (size_t)i * 8) = o0;
  *(float4*)(out + (size_t)i * 8 + 4) = o1;
}

extern "C" void kernel_launch(void* const* d_in, const int* in_sizes, int n_in,
                              void* d_out, int out_size, void* d_ws, size_t ws_size,
                              hipStream_t stream) {
  (void)in_sizes; (void)n_in; (void)out_size; (void)ws_size;
  const float* x = (const float*)d_in[0];
  const int* ei = (const int*)d_in[1];
  const float* W1 = (const float*)d_in[2];
  const float* as1 = (const float*)d_in[3];
  const float* ad1 = (const float*)d_in[4];
  const float* b1 = (const float*)d_in[5];
  const float* g1 = (const float*)d_in[6];
  const float* be1 = (const float*)d_in[7];
  const float* W2 = (const float*)d_in[8];
  const float* as2 = (const float*)d_in[9];
  const float* ad2 = (const float*)d_in[10];
  const float* b2 = (const float*)d_in[11];
  const float* g2 = (const float*)d_in[12];
  const float* be2 = (const float*)d_in[13];
  const float* W3 = (const float*)d_in[14];
  const float* as3 = (const float*)d_in[15];
  const float* ad3 = (const float*)d_in[16];
  const float* b3 = (const float*)d_in[17];
  const float* g3 = (const float*)d_in[18];
  const float* be3 = (const float*)d_in[19];

  unsigned short* Yb = (unsigned short*)d_ws;                    // [NN*128] bf16
  unsigned short* h2 = Yb + (size_t)NN * 128;                    // [NN*128] bf16
  int2* tmpe = (int2*)(h2 + (size_t)NN * 128);                   // [ET]
  float* asrc = (float*)(tmpe + (size_t)ET);                     // [NN*4]
  float* adst = asrc + (size_t)NN * 4;                           // [NN*4]
  float* bnred = adst + (size_t)NN * 4;                          // [256]
  float* scale = bnred + 256;                                    // [128]
  float* shift = scale + 128;                                    // [128]
  int* rowptr = (int*)(shift + 128);                             // [NN+2]
  int* bcnt = rowptr + NN + 2;                                   // [NBK2]
  int* bbase = bcnt + NBK2;                                      // [NBK2+1]
  int* gpos = bbase + NBK2 + 1;                                  // [NBK2]
  int* srcs = gpos + NBK2;                                       // [ET]

  const int GB64 = (NN + 63) / 64;  // 1563

  // ---- CSR build ----
  hipMemsetAsync(bcnt, 0, NBK2 * sizeof(int), stream);
  histb2_k<<<(ET + 1023) / 1024, 256, 0, stream>>>(ei, bcnt);
  scanb2_k<<<1, 512, 0, stream>>>(bcnt, bbase, gpos);
  binscatter_k<<<(ET + EPB - 1) / EPB, 256, 0, stream>>>(ei, gpos, tmpe);
  bucket_build2_k<<<NBK2, 256, 0, stream>>>(tmpe, bbase, rowptr, srcs);

  // ---- Layer 1 ----
  gemm_mfma_k<64, 4, false><<<GB64, 256, 0, stream>>>(x, W1, nullptr, nullptr,
                                                      as1, ad1, h2, asrc, adst);
  hipMemsetAsync(bnred, 0, 256 * sizeof(float), stream);
  gat_agg_k<4, 32><<<NGAT, 256, 0, stream>>>(rowptr, srcs, asrc, adst, h2, b1, Yb, bnred);
  bn2_k<<<1, 128, 0, stream>>>(bnred, g1, be1, scale, shift);

  // ---- Layer 2 ----
  gemm_mfma_k<128, 4, true><<<GB64, 256, 0, stream>>>(Yb, W2, scale, shift,
                                                      as2, ad2, h2, asrc, adst);
  hipMemsetAsync(bnred, 0, 256 * sizeof(float), stream);
  gat_agg_k<4, 32><<<NGAT, 256, 0, stream>>>(rowptr, srcs, asrc, adst, h2, b2, Yb, bnred);
  bn2_k<<<1, 128, 0, stream>>>(bnred, g2, be2, scale, shift);

  // ---- Layer 3 ----
  gemm_mfma_k<128, 1, true><<<GB64, 256, 0, stream>>>(Yb, W3, scale, shift,
                                                      as3, ad3, h2, asrc, adst);
  hipMemsetAsync(bnred, 0, 256 * sizeof(float), stream);
  gat_agg_k<1, 128><<<NGAT, 256, 0, stream>>>(rowptr, srcs, asrc, adst, h2, b3, Yb, bnred);
  bn2_k<<<1, 128, 0, stream>>>(bnred, g3, be3, scale, shift);
  bn3_k<<<(NN * 16 + 255) / 256, 256, 0, stream>>>(Yb, scale, shift, (float*)d_out);
}